// Round 16
// baseline (401.761 us; speedup 1.0000x reference)
//
#include <hip/hip_runtime.h>
#include <hip/hip_bf16.h>
#include <math.h>

typedef __bf16 bf16_t;
typedef __bf16 bf16x8 __attribute__((ext_vector_type(8)));
typedef __bf16 bf16x4 __attribute__((ext_vector_type(4)));
typedef float  f32x4  __attribute__((ext_vector_type(4)));

#define DIM   1024
#define NB    2
#define NL    2048
#define NS    2048
#define NH    16
#define NDH   64
#define NDFF  4096

// inline-asm LDS read: invisible to the waitcnt pass; ordering is carried by
// our explicit vmcnt(0)+s_barrier chain.
#define DS_READ_B128(dst, addr) \
    asm volatile("ds_read_b128 %0, %1" : "=v"(dst) : "v"(addr))
// rule #18: asm reads need an explicit lgkm drain + sched fence before MFMA use
#define LGKM0_FENCE() do { \
    asm volatile("s_waitcnt lgkmcnt(0)" ::: "memory"); \
    __builtin_amdgcn_sched_barrier(0); } while (0)

__device__ __forceinline__ bf16x8 ld_bf16x8(const bf16_t* p) {
    return *reinterpret_cast<const bf16x8*>(p);
}

// async global->LDS, 16B per lane; LDS dest is wave-uniform base + lane*16
__device__ __forceinline__ void gl_lds16(const bf16_t* g, bf16_t* l) {
    __builtin_amdgcn_global_load_lds(
        (const __attribute__((address_space(1))) void*)g,
        (__attribute__((address_space(3))) void*)l, 16, 0, 0);
}

__device__ __forceinline__ unsigned lds_u32(const bf16_t* p) {
    return (unsigned)(uintptr_t)(__attribute__((address_space(3))) const void*)p;
}

// ---------------- weight convert + transpose: fp32 [K,N] -> bf16 [N,K] ----
__global__ __launch_bounds__(256)
void wconv_kernel(const float* __restrict__ in, bf16_t* __restrict__ out, int K, int N)
{
    __shared__ float tile[32][33];
    int n0 = blockIdx.x * 32, k0 = blockIdx.y * 32;
    int tx = threadIdx.x & 31, ty = threadIdx.x >> 5;   // ty 0..7
    #pragma unroll
    for (int j = 0; j < 4; ++j)
        tile[ty + 8*j][tx] = in[(size_t)(k0 + ty + 8*j) * N + n0 + tx];
    __syncthreads();
    #pragma unroll
    for (int j = 0; j < 4; ++j)
        out[(size_t)(n0 + ty + 8*j) * K + k0 + tx] = (bf16_t)tile[tx][ty + 8*j];
}

// ---------------- fp32 -> bf16 elementwise --------------------------------
__global__ __launch_bounds__(256)
void f2b_kernel(const float* __restrict__ in, bf16_t* __restrict__ out)
{
    size_t i = ((size_t)blockIdx.x * 256 + threadIdx.x) * 4;
    float4 v = *reinterpret_cast<const float4*>(in + i);
    bf16x4 o = { (bf16_t)v.x, (bf16_t)v.y, (bf16_t)v.z, (bf16_t)v.w };
    *reinterpret_cast<bf16x4*>(out + i) = o;
}

// ---------------- LayerNorm (fp32 in, bf16 out), D=1024 -------------------
__global__ __launch_bounds__(256)
void ln_kernel(const float* __restrict__ x, const float* __restrict__ wgt,
               const float* __restrict__ bia, bf16_t* __restrict__ out)
{
    int row = blockIdx.x, tid = threadIdx.x;
    float4 xv = reinterpret_cast<const float4*>(x + (size_t)row * DIM)[tid];
    float s1 = xv.x + xv.y + xv.z + xv.w;
    float s2 = xv.x*xv.x + xv.y*xv.y + xv.z*xv.z + xv.w*xv.w;
    #pragma unroll
    for (int off = 32; off > 0; off >>= 1) {
        s1 += __shfl_xor(s1, off, 64);
        s2 += __shfl_xor(s2, off, 64);
    }
    __shared__ float red[8];
    int w = tid >> 6;
    if ((tid & 63) == 0) { red[w] = s1; red[w + 4] = s2; }
    __syncthreads();
    s1 = red[0] + red[1] + red[2] + red[3];
    s2 = red[4] + red[5] + red[6] + red[7];
    float mean = s1 * (1.0f / DIM);
    float var  = s2 * (1.0f / DIM) - mean * mean;
    float rstd = rsqrtf(var + 1e-6f);
    float4 wv = reinterpret_cast<const float4*>(wgt)[tid];
    float4 bv = reinterpret_cast<const float4*>(bia)[tid];
    bf16x4 o = { (bf16_t)((xv.x - mean) * rstd * wv.x + bv.x),
                 (bf16_t)((xv.y - mean) * rstd * wv.y + bv.y),
                 (bf16_t)((xv.z - mean) * rstd * wv.z + bv.z),
                 (bf16_t)((xv.w - mean) * rstd * wv.w + bv.w) };
    reinterpret_cast<bf16x4*>(out + (size_t)row * DIM)[tid] = o;
}

// ---------------- GEMM 128-tile, BK=64, 2-stage, 8 waves (unchanged) ------
template<int EPI, int BM, int BN>
__global__ __launch_bounds__(512)
void gemm_kernel(const bf16_t* __restrict__ A, const bf16_t* __restrict__ BT,
                 const float* __restrict__ bias, const float* __restrict__ res,
                 void* __restrict__ out, int M, int N, int K)
{
    constexpr int WM = BM / 2, WN = BN / 4;     // 2x4 wave grid
    constexpr int AM = WM / 16, AN = WN / 16;
    constexpr int ABE = (BM + BN) * 64;         // elems per stage
    __shared__ __align__(16) bf16_t lds[2 * ABE];

    int tid = threadIdx.x;
    int lane = tid & 63, w = tid >> 6;          // 8 waves
    int wr = w >> 2, wc = w & 3;
    int la = lane & 15, lg = lane >> 4;

    int gx = gridDim.x;
    int flat = blockIdx.y * gx + blockIdx.x;
    int cpx = gx >> 3;
    int xcd = flat & 7, loc = flat >> 3;
    int m0 = (loc / cpx) * BM;
    int n0 = (xcd * cpx + loc % cpx) * BN;

    f32x4 acc[AM][AN] = {};

    int srl  = lane >> 3;                       // 0..7
    int sch  = lane & 7;
    int scol = ((sch ^ srl) * 8);
    const bf16_t* Ap = A  + (size_t)(m0 + w * 8 + srl) * K + scol;
    const bf16_t* Bp = BT + (size_t)(n0 + w * 8 + srl) * K + scol;

    auto stage = [&](int t, int buf) {
        int k0 = t * 64;
        bf16_t* base = &lds[buf * ABE];
        #pragma unroll
        for (int i = 0; i < BM / 64; ++i)
            gl_lds16(Ap + ((size_t)i * 64) * K + k0, base + (i * 64 + w * 8) * 64);
        #pragma unroll
        for (int i = 0; i < BN / 64; ++i)
            gl_lds16(Bp + ((size_t)i * 64) * K + k0, base + (BM + i * 64 + w * 8) * 64);
    };

    unsigned ldsb = lds_u32(lds);
    unsigned kla = la & 7;                      // read-side swizzle key
    unsigned a_base = ldsb + (wr * WM + la) * 128 + ((lg ^ kla) * 16);
    unsigned b_base = ldsb + BM * 128 + (wc * WN + la) * 128 + ((lg ^ kla) * 16);

    auto compute = [&](int buf) {
        unsigned dB = (unsigned)(buf * ABE * 2);
        bf16x8 af[AM], bfr[AN];
        #pragma unroll
        for (int mi = 0; mi < AM; ++mi)
            DS_READ_B128(af[mi], a_base + dB + mi * 2048);
        #pragma unroll
        for (int ni = 0; ni < AN; ++ni)
            DS_READ_B128(bfr[ni], b_base + dB + ni * 2048);
        LGKM0_FENCE();
        __builtin_amdgcn_s_setprio(1);
        #pragma unroll
        for (int mi = 0; mi < AM; ++mi)
            #pragma unroll
            for (int ni = 0; ni < AN; ++ni)
                acc[mi][ni] = __builtin_amdgcn_mfma_f32_16x16x32_bf16(
                                  af[mi], bfr[ni], acc[mi][ni], 0, 0, 0);
        __builtin_amdgcn_s_setprio(0);
        #pragma unroll
        for (int mi = 0; mi < AM; ++mi)
            DS_READ_B128(af[mi], (a_base + dB + mi * 2048) ^ 64u);
        #pragma unroll
        for (int ni = 0; ni < AN; ++ni)
            DS_READ_B128(bfr[ni], (b_base + dB + ni * 2048) ^ 64u);
        LGKM0_FENCE();
        __builtin_amdgcn_s_setprio(1);
        #pragma unroll
        for (int mi = 0; mi < AM; ++mi)
            #pragma unroll
            for (int ni = 0; ni < AN; ++ni)
                acc[mi][ni] = __builtin_amdgcn_mfma_f32_16x16x32_bf16(
                                  af[mi], bfr[ni], acc[mi][ni], 0, 0, 0);
        __builtin_amdgcn_s_setprio(0);
    };

    int nt = K / 64;
    stage(0, 0);
    for (int t = 0; t < nt; ++t) {
        asm volatile("s_waitcnt vmcnt(0)" ::: "memory");   // stage(t) landed
        __builtin_amdgcn_s_barrier();
        __builtin_amdgcn_sched_barrier(0);
        if (t + 1 < nt) stage(t + 1, (t + 1) & 1);         // opposite buffer
        compute(t & 1);
    }

    #pragma unroll
    for (int mi = 0; mi < AM; ++mi) {
        #pragma unroll
        for (int ni = 0; ni < AN; ++ni) {
            #pragma unroll
            for (int i = 0; i < 4; ++i) {
                int row = m0 + wr * WM + mi * 16 + lg * 4 + i;
                int col = n0 + wc * WN + ni * 16 + la;
                float v = acc[mi][ni][i] + bias[col];
                if (EPI == 1) v = 0.5f * v * (1.0f + erff(v * 0.70710678118f));
                if (EPI == 2)
                    ((float*)out)[(size_t)row * N + col] = res[(size_t)row * N + col] + v;
                else
                    ((bf16_t*)out)[(size_t)row * N + col] = (bf16_t)v;
            }
        }
    }
}

// ---------------- Flash attention, QBLK=128, 8 waves, 2-way split-S -------
// Occupancy fix: grid was 512 blocks = 2/CU (22% occupancy, nothing
// saturated). grid.z=2 splits each block's s-tile range in half -> 1024
// blocks = 4/CU = 32 waves/CU, and better causal load balance. No-max
// softmax makes partials additive: blocks write unnormalized o (f32) and l;
// a combine kernel sums + normalizes. Causal ntot>=2 so splits never empty.
template<bool CAUSAL>
__global__ __launch_bounds__(512)
void attn_kernel(const bf16_t* __restrict__ Q, int qs,
                 const bf16_t* __restrict__ Kp, int ks,
                 const bf16_t* __restrict__ Vp, int vs,
                 float* __restrict__ o_part, float* __restrict__ l_part,
                 int L, int S)
{
    __shared__ __align__(16) bf16_t Ks[64 * 64];
    __shared__ __align__(16) bf16_t Vt[64 * 64];      // transposed: Vt[d][s]
    __shared__ __align__(16) bf16_t Ps[8][16 * 64];   // per-wave P tile

    int tid = threadIdx.x, lane = tid & 63, w = tid >> 6;   // 8 waves
    int la = lane & 15, lg = lane >> 4;
    int qtile = (CAUSAL ? (gridDim.x - 1 - blockIdx.x) : blockIdx.x) * 128;
    int b = blockIdx.y >> 4, h = blockIdx.y & 15;
    int split = blockIdx.z;

    const bf16_t* qb = Q  + (size_t)(b * L) * qs + h * 64;
    const bf16_t* kb = Kp + (size_t)(b * S) * ks + h * 64;
    const bf16_t* vb = Vp + (size_t)(b * S) * vs + h * 64;

    int qrow = qtile + w * 16 + la;
    bf16x8 qf0 = ld_bf16x8(qb + (size_t)qrow * qs + lg * 8);
    bf16x8 qf1 = ld_bf16x8(qb + (size_t)qrow * qs + 32 + lg * 8);
    #pragma unroll
    for (int j = 0; j < 8; ++j) {   // fold 1/8 scale into Q (exact pow-2)
        qf0[j] = qf0[j] * (bf16_t)0.125f;
        qf1[j] = qf1[j] * (bf16_t)0.125f;
    }

    f32x4 zero = {0.f, 0.f, 0.f, 0.f};
    f32x4 o[4];
    #pragma unroll
    for (int dt = 0; dt < 4; ++dt) o[dt] = zero;
    float lpart[4] = {0.f, 0.f, 0.f, 0.f};

    // staging geometry (512 threads cover each 64x64 tile in one pass)
    int rk    = tid >> 3;          // K: s-row 0..63
    int ck8   = tid & 7;           // K: d-chunk
    int sv    = tid & 63;          // V: s-col 0..63
    int dbase = (tid >> 6) * 8;    // V: d-slice base 0..56
    int r7 = la & 7;

    int n_full = (CAUSAL ? qtile : S) / 64;     // unmasked s-tiles
    int ntot = CAUSAL ? (n_full + 2) : (S / 64);
    int mid = ntot >> 1;
    int lo = split ? mid : 0;
    int hi = split ? ntot : mid;

    bf16x8 kr = ld_bf16x8(kb + (size_t)(lo * 64 + rk) * ks + ck8 * 8);
    bf16x8 vr = ld_bf16x8(vb + (size_t)(lo * 64 + sv) * vs + dbase);

    for (int it = lo; it < hi; ++it) {
        int s0 = it * 64;
        bool diag = CAUSAL && (it >= n_full);

        __syncthreads();
        *reinterpret_cast<bf16x8*>(&Ks[rk * 64 + ((ck8 ^ (rk & 7)) * 8)]) = kr;
        #pragma unroll
        for (int j = 0; j < 8; ++j)
            Vt[(dbase + j) * 64 + (sv ^ (j << 3))] = vr[j];   // (dbase+j)&7 == j
        __syncthreads();

        if (it + 1 < hi) {   // prefetch t+1 after barrier: hides under compute
            int s1 = s0 + 64;
            kr = ld_bf16x8(kb + (size_t)(s1 + rk) * ks + ck8 * 8);
            vr = ld_bf16x8(vb + (size_t)(s1 + sv) * vs + dbase);
        }

        // QK^T (Q pre-scaled)
        f32x4 sf[4];
        #pragma unroll
        for (int ct = 0; ct < 4; ++ct) {
            const bf16_t* kp = &Ks[(ct * 16 + la) * 64];
            bf16x8 k0 = ld_bf16x8(kp + ((lg ^ r7) * 8));
            bf16x8 k1 = ld_bf16x8(kp + (((4 + lg) ^ r7) * 8));
            f32x4 z = zero;
            __builtin_amdgcn_s_setprio(1);
            z = __builtin_amdgcn_mfma_f32_16x16x32_bf16(qf0, k0, z, 0, 0, 0);
            z = __builtin_amdgcn_mfma_f32_16x16x32_bf16(qf1, k1, z, 0, 0, 0);
            __builtin_amdgcn_s_setprio(0);
            sf[ct] = z;
        }

        // softmax-lite: p = exp(s), per-lane l partials, P -> LDS (swizzled)
        #pragma unroll
        for (int ct = 0; ct < 4; ++ct) {
            #pragma unroll
            for (int i = 0; i < 4; ++i) {
                float p = __expf(sf[ct][i]);
                if (diag) {
                    int sg = s0 + ct * 16 + la;
                    int qg = qtile + w * 16 + lg * 4 + i;
                    if (sg > qg) p = 0.f;
                }
                lpart[i] += p;
                int row = lg * 4 + i;
                Ps[w][row * 64 + ((ct * 16 + la) ^ ((row & 7) << 3))] = (bf16_t)p;
            }
        }
        // no barrier: Ps is per-wave; same-wave ds RAW ordered by lgkmcnt

        bf16x8 pa0 = ld_bf16x8(&Ps[w][la * 64 + ((lg ^ r7) * 8)]);
        bf16x8 pa1 = ld_bf16x8(&Ps[w][la * 64 + (((4 + lg) ^ r7) * 8)]);
        __builtin_amdgcn_s_setprio(1);
        #pragma unroll
        for (int dt = 0; dt < 4; ++dt) {
            const bf16_t* vp = &Vt[(dt * 16 + la) * 64];
            bf16x8 v0 = ld_bf16x8(vp + ((lg ^ r7) * 8));
            bf16x8 v1 = ld_bf16x8(vp + (((4 + lg) ^ r7) * 8));
            o[dt] = __builtin_amdgcn_mfma_f32_16x16x32_bf16(pa0, v0, o[dt], 0, 0, 0);
            o[dt] = __builtin_amdgcn_mfma_f32_16x16x32_bf16(pa1, v1, o[dt], 0, 0, 0);
        }
        __builtin_amdgcn_s_setprio(0);
    }

    // epilogue: l-reduce across the 16 la-lanes, write unnormalized partials
    #pragma unroll
    for (int off = 1; off < 16; off <<= 1)
        #pragma unroll
        for (int i = 0; i < 4; ++i)
            lpart[i] += __shfl_xor(lpart[i], off, 64);

    #pragma unroll
    for (int i = 0; i < 4; ++i) {
        size_t rowg = (size_t)(b * L + qtile + w * 16 + lg * 4 + i);
        #pragma unroll
        for (int dt = 0; dt < 4; ++dt)
            o_part[((size_t)split * 4096 + rowg) * 1024 + h * 64 + dt * 16 + la] = o[dt][i];
        if (la == 0)
            l_part[((size_t)split * 4096 + rowg) * 16 + h] = lpart[i];
    }
}

// ---------------- attention combine: out = (o0+o1) / (l0+l1), bf16 --------
__global__ __launch_bounds__(256)
void attn_comb_kernel(const float* __restrict__ op, const float* __restrict__ lp,
                      bf16_t* __restrict__ out)
{
    size_t i = ((size_t)blockIdx.x * 256 + threadIdx.x) * 4;
    const size_t OS = (size_t)4096 * 1024;
    float4 a = *reinterpret_cast<const float4*>(op + i);
    float4 c = *reinterpret_cast<const float4*>(op + OS + i);
    size_t row = i >> 10;
    int h = (int)((i & 1023) >> 6);
    float l = lp[row * 16 + h] + lp[(4096 + row) * 16 + h];
    float rl = 1.0f / l;
    bf16x4 o = { (bf16_t)((a.x + c.x) * rl), (bf16_t)((a.y + c.y) * rl),
                 (bf16_t)((a.z + c.z) * rl), (bf16_t)((a.w + c.w) * rl) };
    *reinterpret_cast<bf16x4*>(out + i) = o;
}

// ---------------------------------------------------------------------------
extern "C" void kernel_launch(void* const* d_in, const int* in_sizes, int n_in,
                              void* d_out, int out_size, void* d_ws, size_t ws_size,
                              hipStream_t stream)
{
    const float* input     = (const float*)d_in[0];
    const float* source    = (const float*)d_in[1];
    const float* ln_self_w = (const float*)d_in[4];
    const float* ln_self_b = (const float*)d_in[5];
    const float* w_qkv     = (const float*)d_in[6];
    const float* b_qkv     = (const float*)d_in[7];
    const float* w_so      = (const float*)d_in[8];
    const float* b_so      = (const float*)d_in[9];
    const float* ln_cross_w= (const float*)d_in[10];
    const float* ln_cross_b= (const float*)d_in[11];
    const float* w_q       = (const float*)d_in[12];
    const float* b_q       = (const float*)d_in[13];
    const float* w_kv      = (const float*)d_in[14];
    const float* b_kv      = (const float*)d_in[15];
    const float* w_co      = (const float*)d_in[16];
    const float* b_co      = (const float*)d_in[17];
    const float* ln_mlp_w  = (const float*)d_in[18];
    const float* ln_mlp_b  = (const float*)d_in[19];
    const float* w_ff1     = (const float*)d_in[20];
    const float* b_ff1     = (const float*)d_in[21];
    const float* w_ff2     = (const float*)d_in[22];
    const float* b_ff2     = (const float*)d_in[23];

    const int M = NB * NL;   // 4096 rows

    char* ws = (char*)d_ws;
    size_t off = 0;
    auto alloc = [&](size_t bytes) { char* p = ws + off; off += (bytes + 255) & ~(size_t)255; return p; };

    bf16_t* wT_qkv = (bf16_t*)alloc((size_t)3072 * 1024 * 2);
    bf16_t* wT_so  = (bf16_t*)alloc((size_t)1024 * 1024 * 2);
    bf16_t* wT_q   = (bf16_t*)alloc((size_t)1024 * 1024 * 2);
    bf16_t* wT_kv  = (bf16_t*)alloc((size_t)2048 * 1024 * 2);
    bf16_t* wT_co  = (bf16_t*)alloc((size_t)1024 * 1024 * 2);
    bf16_t* wT_ff1 = (bf16_t*)alloc((size_t)4096 * 1024 * 2);
    bf16_t* wT_ff2 = (bf16_t*)alloc((size_t)1024 * 4096 * 2);
    bf16_t* srcb   = (bf16_t*)alloc((size_t)M * 1024 * 2);
    bf16_t* hbuf   = (bf16_t*)alloc((size_t)M * 1024 * 2);
    bf16_t* qkvb   = (bf16_t*)alloc((size_t)M * 3072 * 2);
    bf16_t* attnb  = (bf16_t*)alloc((size_t)M * 1024 * 2);
    bf16_t* qcb    = (bf16_t*)alloc((size_t)M * 1024 * 2);
    bf16_t* kvcb   = (bf16_t*)alloc((size_t)M * 2048 * 2);
    float*  xbuf   = (float*) alloc((size_t)M * 1024 * 4);
    bf16_t* ff1b   = (bf16_t*)alloc((size_t)M * 4096 * 2);
    (void)ws_size; (void)n_in; (void)in_sizes; (void)out_size;

    // split-S attention partials alias DEAD buffers at their use points:
    // - o_part (2 x 16 MB f32) -> ff1b (32 MB, written only by ff1 GEMM later)
    // - self-attn l_part -> qcb (written by q GEMM after self combine)
    // - cross-attn l_part -> hbuf (dead between q GEMM and ln_mlp)
    float* o_part = (float*)ff1b;

    // weights -> bf16 transposed
    wconv_kernel<<<dim3(3072/32, 1024/32), 256, 0, stream>>>(w_qkv, wT_qkv, 1024, 3072);
    wconv_kernel<<<dim3(1024/32, 1024/32), 256, 0, stream>>>(w_so,  wT_so,  1024, 1024);
    wconv_kernel<<<dim3(1024/32, 1024/32), 256, 0, stream>>>(w_q,   wT_q,   1024, 1024);
    wconv_kernel<<<dim3(2048/32, 1024/32), 256, 0, stream>>>(w_kv,  wT_kv,  1024, 2048);
    wconv_kernel<<<dim3(1024/32, 1024/32), 256, 0, stream>>>(w_co,  wT_co,  1024, 1024);
    wconv_kernel<<<dim3(4096/32, 1024/32), 256, 0, stream>>>(w_ff1, wT_ff1, 1024, 4096);
    wconv_kernel<<<dim3(1024/32, 4096/32), 256, 0, stream>>>(w_ff2, wT_ff2, 4096, 1024);
    // source -> bf16
    f2b_kernel<<<(M * 1024) / (256 * 4), 256, 0, stream>>>(source, srcb);

    // ---- self-attention block ----
    ln_kernel<<<M, 256, 0, stream>>>(input, ln_self_w, ln_self_b, hbuf);
    gemm_kernel<0,128,128><<<dim3(3072/128, M/128), 512, 0, stream>>>(hbuf, wT_qkv, b_qkv, nullptr, qkvb, M, 3072, 1024);
    attn_kernel<true><<<dim3(NL/128, NB*NH, 2), 512, 0, stream>>>(qkvb, 3072, qkvb + 1024, 3072, qkvb + 2048, 3072,
                                                                  o_part, (float*)qcb, NL, NL);
    attn_comb_kernel<<<(M * 1024) / (256 * 4), 256, 0, stream>>>(o_part, (float*)qcb, attnb);
    gemm_kernel<2,128,64><<<dim3(1024/64, M/128), 512, 0, stream>>>(attnb, wT_so, b_so, input, xbuf, M, 1024, 1024);

    // ---- cross-attention block ----
    ln_kernel<<<M, 256, 0, stream>>>(xbuf, ln_cross_w, ln_cross_b, hbuf);
    gemm_kernel<0,128,64><<<dim3(1024/64, M/128), 512, 0, stream>>>(hbuf, wT_q, b_q, nullptr, qcb, M, 1024, 1024);
    gemm_kernel<0,128,128><<<dim3(2048/128, M/128), 512, 0, stream>>>(srcb, wT_kv, b_kv, nullptr, kvcb, M, 2048, 1024);
    attn_kernel<false><<<dim3(NL/128, NB*NH, 2), 512, 0, stream>>>(qcb, 1024, kvcb, 2048, kvcb + 1024, 2048,
                                                                   o_part, (float*)hbuf, NL, NS);
    attn_comb_kernel<<<(M * 1024) / (256 * 4), 256, 0, stream>>>(o_part, (float*)hbuf, attnb);
    gemm_kernel<2,128,64><<<dim3(1024/64, M/128), 512, 0, stream>>>(attnb, wT_co, b_co, xbuf, xbuf, M, 1024, 1024);

    // ---- MLP block ----
    ln_kernel<<<M, 256, 0, stream>>>(xbuf, ln_mlp_w, ln_mlp_b, hbuf);
    gemm_kernel<1,128,128><<<dim3(4096/128, M/128), 512, 0, stream>>>(hbuf, wT_ff1, b_ff1, nullptr, ff1b, M, 4096, 1024);
    gemm_kernel<2,128,64><<<dim3(1024/64, M/128), 512, 0, stream>>>(ff1b, wT_ff2, b_ff2, xbuf, d_out, M, 1024, 4096);
}

// Round 17
// 382.605 us; speedup vs baseline: 1.0501x; 1.0501x over previous
//
#include <hip/hip_runtime.h>
#include <hip/hip_bf16.h>
#include <math.h>

typedef __bf16 bf16_t;
typedef __bf16 bf16x8 __attribute__((ext_vector_type(8)));
typedef __bf16 bf16x4 __attribute__((ext_vector_type(4)));
typedef float  f32x4  __attribute__((ext_vector_type(4)));

#define DIM   1024
#define NB    2
#define NL    2048
#define NS    2048
#define NH    16
#define NDH   64
#define NDFF  4096

// inline-asm LDS read: invisible to the waitcnt pass; ordering is carried by
// our explicit vmcnt(0)+s_barrier chain.
#define DS_READ_B128(dst, addr) \
    asm volatile("ds_read_b128 %0, %1" : "=v"(dst) : "v"(addr))
// rule #18: asm reads need an explicit lgkm drain + sched fence before MFMA use
#define LGKM0_FENCE() do { \
    asm volatile("s_waitcnt lgkmcnt(0)" ::: "memory"); \
    __builtin_amdgcn_sched_barrier(0); } while (0)

__device__ __forceinline__ bf16x8 ld_bf16x8(const bf16_t* p) {
    return *reinterpret_cast<const bf16x8*>(p);
}

// async global->LDS, 16B per lane; LDS dest is wave-uniform base + lane*16
__device__ __forceinline__ void gl_lds16(const bf16_t* g, bf16_t* l) {
    __builtin_amdgcn_global_load_lds(
        (const __attribute__((address_space(1))) void*)g,
        (__attribute__((address_space(3))) void*)l, 16, 0, 0);
}

__device__ __forceinline__ unsigned lds_u32(const bf16_t* p) {
    return (unsigned)(uintptr_t)(__attribute__((address_space(3))) const void*)p;
}

// ---------------- weight convert + transpose: fp32 [K,N] -> bf16 [N,K] ----
__global__ __launch_bounds__(256)
void wconv_kernel(const float* __restrict__ in, bf16_t* __restrict__ out, int K, int N)
{
    __shared__ float tile[32][33];
    int n0 = blockIdx.x * 32, k0 = blockIdx.y * 32;
    int tx = threadIdx.x & 31, ty = threadIdx.x >> 5;   // ty 0..7
    #pragma unroll
    for (int j = 0; j < 4; ++j)
        tile[ty + 8*j][tx] = in[(size_t)(k0 + ty + 8*j) * N + n0 + tx];
    __syncthreads();
    #pragma unroll
    for (int j = 0; j < 4; ++j)
        out[(size_t)(n0 + ty + 8*j) * K + k0 + tx] = (bf16_t)tile[tx][ty + 8*j];
}

// ---------------- fp32 -> bf16 elementwise --------------------------------
__global__ __launch_bounds__(256)
void f2b_kernel(const float* __restrict__ in, bf16_t* __restrict__ out)
{
    size_t i = ((size_t)blockIdx.x * 256 + threadIdx.x) * 4;
    float4 v = *reinterpret_cast<const float4*>(in + i);
    bf16x4 o = { (bf16_t)v.x, (bf16_t)v.y, (bf16_t)v.z, (bf16_t)v.w };
    *reinterpret_cast<bf16x4*>(out + i) = o;
}

// ---------------- LayerNorm (fp32 in, bf16 out), D=1024 -------------------
__global__ __launch_bounds__(256)
void ln_kernel(const float* __restrict__ x, const float* __restrict__ wgt,
               const float* __restrict__ bia, bf16_t* __restrict__ out)
{
    int row = blockIdx.x, tid = threadIdx.x;
    float4 xv = reinterpret_cast<const float4*>(x + (size_t)row * DIM)[tid];
    float s1 = xv.x + xv.y + xv.z + xv.w;
    float s2 = xv.x*xv.x + xv.y*xv.y + xv.z*xv.z + xv.w*xv.w;
    #pragma unroll
    for (int off = 32; off > 0; off >>= 1) {
        s1 += __shfl_xor(s1, off, 64);
        s2 += __shfl_xor(s2, off, 64);
    }
    __shared__ float red[8];
    int w = tid >> 6;
    if ((tid & 63) == 0) { red[w] = s1; red[w + 4] = s2; }
    __syncthreads();
    s1 = red[0] + red[1] + red[2] + red[3];
    s2 = red[4] + red[5] + red[6] + red[7];
    float mean = s1 * (1.0f / DIM);
    float var  = s2 * (1.0f / DIM) - mean * mean;
    float rstd = rsqrtf(var + 1e-6f);
    float4 wv = reinterpret_cast<const float4*>(wgt)[tid];
    float4 bv = reinterpret_cast<const float4*>(bia)[tid];
    bf16x4 o = { (bf16_t)((xv.x - mean) * rstd * wv.x + bv.x),
                 (bf16_t)((xv.y - mean) * rstd * wv.y + bv.y),
                 (bf16_t)((xv.z - mean) * rstd * wv.z + bv.z),
                 (bf16_t)((xv.w - mean) * rstd * wv.w + bv.w) };
    reinterpret_cast<bf16x4*>(out + (size_t)row * DIM)[tid] = o;
}

// ---------------- GEMM 128-tile, BK=64, 2-stage, 8 waves (unchanged) ------
template<int EPI, int BM, int BN>
__global__ __launch_bounds__(512)
void gemm_kernel(const bf16_t* __restrict__ A, const bf16_t* __restrict__ BT,
                 const float* __restrict__ bias, const float* __restrict__ res,
                 void* __restrict__ out, int M, int N, int K)
{
    constexpr int WM = BM / 2, WN = BN / 4;     // 2x4 wave grid
    constexpr int AM = WM / 16, AN = WN / 16;
    constexpr int ABE = (BM + BN) * 64;         // elems per stage
    __shared__ __align__(16) bf16_t lds[2 * ABE];

    int tid = threadIdx.x;
    int lane = tid & 63, w = tid >> 6;          // 8 waves
    int wr = w >> 2, wc = w & 3;
    int la = lane & 15, lg = lane >> 4;

    int gx = gridDim.x;
    int flat = blockIdx.y * gx + blockIdx.x;
    int cpx = gx >> 3;
    int xcd = flat & 7, loc = flat >> 3;
    int m0 = (loc / cpx) * BM;
    int n0 = (xcd * cpx + loc % cpx) * BN;

    f32x4 acc[AM][AN] = {};

    int srl  = lane >> 3;                       // 0..7
    int sch  = lane & 7;
    int scol = ((sch ^ srl) * 8);
    const bf16_t* Ap = A  + (size_t)(m0 + w * 8 + srl) * K + scol;
    const bf16_t* Bp = BT + (size_t)(n0 + w * 8 + srl) * K + scol;

    auto stage = [&](int t, int buf) {
        int k0 = t * 64;
        bf16_t* base = &lds[buf * ABE];
        #pragma unroll
        for (int i = 0; i < BM / 64; ++i)
            gl_lds16(Ap + ((size_t)i * 64) * K + k0, base + (i * 64 + w * 8) * 64);
        #pragma unroll
        for (int i = 0; i < BN / 64; ++i)
            gl_lds16(Bp + ((size_t)i * 64) * K + k0, base + (BM + i * 64 + w * 8) * 64);
    };

    unsigned ldsb = lds_u32(lds);
    unsigned kla = la & 7;                      // read-side swizzle key
    unsigned a_base = ldsb + (wr * WM + la) * 128 + ((lg ^ kla) * 16);
    unsigned b_base = ldsb + BM * 128 + (wc * WN + la) * 128 + ((lg ^ kla) * 16);

    auto compute = [&](int buf) {
        unsigned dB = (unsigned)(buf * ABE * 2);
        bf16x8 af[AM], bfr[AN];
        #pragma unroll
        for (int mi = 0; mi < AM; ++mi)
            DS_READ_B128(af[mi], a_base + dB + mi * 2048);
        #pragma unroll
        for (int ni = 0; ni < AN; ++ni)
            DS_READ_B128(bfr[ni], b_base + dB + ni * 2048);
        LGKM0_FENCE();
        __builtin_amdgcn_s_setprio(1);
        #pragma unroll
        for (int mi = 0; mi < AM; ++mi)
            #pragma unroll
            for (int ni = 0; ni < AN; ++ni)
                acc[mi][ni] = __builtin_amdgcn_mfma_f32_16x16x32_bf16(
                                  af[mi], bfr[ni], acc[mi][ni], 0, 0, 0);
        __builtin_amdgcn_s_setprio(0);
        #pragma unroll
        for (int mi = 0; mi < AM; ++mi)
            DS_READ_B128(af[mi], (a_base + dB + mi * 2048) ^ 64u);
        #pragma unroll
        for (int ni = 0; ni < AN; ++ni)
            DS_READ_B128(bfr[ni], (b_base + dB + ni * 2048) ^ 64u);
        LGKM0_FENCE();
        __builtin_amdgcn_s_setprio(1);
        #pragma unroll
        for (int mi = 0; mi < AM; ++mi)
            #pragma unroll
            for (int ni = 0; ni < AN; ++ni)
                acc[mi][ni] = __builtin_amdgcn_mfma_f32_16x16x32_bf16(
                                  af[mi], bfr[ni], acc[mi][ni], 0, 0, 0);
        __builtin_amdgcn_s_setprio(0);
    };

    int nt = K / 64;
    stage(0, 0);
    for (int t = 0; t < nt; ++t) {
        asm volatile("s_waitcnt vmcnt(0)" ::: "memory");   // stage(t) landed
        __builtin_amdgcn_s_barrier();
        __builtin_amdgcn_sched_barrier(0);
        if (t + 1 < nt) stage(t + 1, (t + 1) & 1);         // opposite buffer
        compute(t & 1);
    }

    #pragma unroll
    for (int mi = 0; mi < AM; ++mi) {
        #pragma unroll
        for (int ni = 0; ni < AN; ++ni) {
            #pragma unroll
            for (int i = 0; i < 4; ++i) {
                int row = m0 + wr * WM + mi * 16 + lg * 4 + i;
                int col = n0 + wc * WN + ni * 16 + la;
                float v = acc[mi][ni][i] + bias[col];
                if (EPI == 1) v = 0.5f * v * (1.0f + erff(v * 0.70710678118f));
                if (EPI == 2)
                    ((float*)out)[(size_t)row * N + col] = res[(size_t)row * N + col] + v;
                else
                    ((bf16_t*)out)[(size_t)row * N + col] = (bf16_t)v;
            }
        }
    }
}

// ---------------- Flash attention, QBLK=128, 8 waves, ping-pong K/V -------
// Revert split-S (regressed: LDS pipe is the shared per-CU choke, more
// blocks just split it). New lever: double-buffered K/V -> ONE barrier per
// s-tile (was 2). Writer of buf b at iter it+2 passes barrier(it+1), which
// every wave reaches only after finishing compute(it) -> readers/writer
// separation preserved. Ps per-wave (same-wave lgkm order). LDS 48 KB.
template<bool CAUSAL>
__global__ __launch_bounds__(512)
void attn_kernel(const bf16_t* __restrict__ Q, int qs,
                 const bf16_t* __restrict__ Kp, int ks,
                 const bf16_t* __restrict__ Vp, int vs,
                 bf16_t* __restrict__ O, int os, int L, int S)
{
    __shared__ __align__(16) bf16_t Ks[2][64 * 64];
    __shared__ __align__(16) bf16_t Vt[2][64 * 64];   // transposed: Vt[d][s]
    __shared__ __align__(16) bf16_t Ps[8][16 * 64];   // per-wave P tile

    int tid = threadIdx.x, lane = tid & 63, w = tid >> 6;   // 8 waves
    int la = lane & 15, lg = lane >> 4;
    int qtile = (CAUSAL ? (gridDim.x - 1 - blockIdx.x) : blockIdx.x) * 128;
    int b = blockIdx.y >> 4, h = blockIdx.y & 15;

    const bf16_t* qb = Q  + (size_t)(b * L) * qs + h * 64;
    const bf16_t* kb = Kp + (size_t)(b * S) * ks + h * 64;
    const bf16_t* vb = Vp + (size_t)(b * S) * vs + h * 64;
    bf16_t*       ob = O  + (size_t)(b * L) * os + h * 64;

    int qrow = qtile + w * 16 + la;
    bf16x8 qf0 = ld_bf16x8(qb + (size_t)qrow * qs + lg * 8);
    bf16x8 qf1 = ld_bf16x8(qb + (size_t)qrow * qs + 32 + lg * 8);
    #pragma unroll
    for (int j = 0; j < 8; ++j) {   // fold 1/8 scale into Q (exact pow-2)
        qf0[j] = qf0[j] * (bf16_t)0.125f;
        qf1[j] = qf1[j] * (bf16_t)0.125f;
    }

    f32x4 zero = {0.f, 0.f, 0.f, 0.f};
    f32x4 o[4];
    #pragma unroll
    for (int dt = 0; dt < 4; ++dt) o[dt] = zero;
    float lpart[4] = {0.f, 0.f, 0.f, 0.f};

    // staging geometry (512 threads cover each 64x64 tile in one pass)
    int rk    = tid >> 3;          // K: s-row 0..63
    int ck8   = tid & 7;           // K: d-chunk
    int sv    = tid & 63;          // V: s-col 0..63
    int dbase = (tid >> 6) * 8;    // V: d-slice base 0..56
    int r7 = la & 7;

    int n_full = (CAUSAL ? qtile : S) / 64;     // unmasked s-tiles
    int nit = n_full + (CAUSAL ? 2 : 0);        // causal: 2 diagonal tiles

    bf16x8 kr = ld_bf16x8(kb + (size_t)rk * ks + ck8 * 8);
    bf16x8 vr = ld_bf16x8(vb + (size_t)sv * vs + dbase);

    for (int it = 0; it < nit; ++it) {
        int s0 = it * 64;
        bool diag = CAUSAL && (it >= n_full);
        bf16_t* Kb = Ks[it & 1];
        bf16_t* Vb = Vt[it & 1];

        // write buf[it&1]; safe vs compute(it-2)'s readers (barrier(it-1)
        // between), runs concurrently with compute(it-1) on the other buf
        *reinterpret_cast<bf16x8*>(&Kb[rk * 64 + ((ck8 ^ (rk & 7)) * 8)]) = kr;
        #pragma unroll
        for (int j = 0; j < 8; ++j)
            Vb[(dbase + j) * 64 + (sv ^ (j << 3))] = vr[j];   // (dbase+j)&7 == j
        __syncthreads();   // buf[it&1] ready for all waves

        if (it + 1 < nit) {   // prefetch t+1: hides under compute
            int s1 = s0 + 64;
            kr = ld_bf16x8(kb + (size_t)(s1 + rk) * ks + ck8 * 8);
            vr = ld_bf16x8(vb + (size_t)(s1 + sv) * vs + dbase);
        }

        // QK^T (Q pre-scaled)
        f32x4 sf[4];
        #pragma unroll
        for (int ct = 0; ct < 4; ++ct) {
            const bf16_t* kp = &Kb[(ct * 16 + la) * 64];
            bf16x8 k0 = ld_bf16x8(kp + ((lg ^ r7) * 8));
            bf16x8 k1 = ld_bf16x8(kp + (((4 + lg) ^ r7) * 8));
            f32x4 z = zero;
            __builtin_amdgcn_s_setprio(1);
            z = __builtin_amdgcn_mfma_f32_16x16x32_bf16(qf0, k0, z, 0, 0, 0);
            z = __builtin_amdgcn_mfma_f32_16x16x32_bf16(qf1, k1, z, 0, 0, 0);
            __builtin_amdgcn_s_setprio(0);
            sf[ct] = z;
        }

        // softmax-lite: p = exp(s), per-lane l partials, P -> LDS (swizzled)
        #pragma unroll
        for (int ct = 0; ct < 4; ++ct) {
            #pragma unroll
            for (int i = 0; i < 4; ++i) {
                float p = __expf(sf[ct][i]);
                if (diag) {
                    int sg = s0 + ct * 16 + la;
                    int qg = qtile + w * 16 + lg * 4 + i;
                    if (sg > qg) p = 0.f;
                }
                lpart[i] += p;
                int row = lg * 4 + i;
                Ps[w][row * 64 + ((ct * 16 + la) ^ ((row & 7) << 3))] = (bf16_t)p;
            }
        }
        // no barrier: Ps is per-wave; same-wave ds RAW ordered by lgkmcnt

        bf16x8 pa0 = ld_bf16x8(&Ps[w][la * 64 + ((lg ^ r7) * 8)]);
        bf16x8 pa1 = ld_bf16x8(&Ps[w][la * 64 + (((4 + lg) ^ r7) * 8)]);
        __builtin_amdgcn_s_setprio(1);
        #pragma unroll
        for (int dt = 0; dt < 4; ++dt) {
            const bf16_t* vp = &Vb[(dt * 16 + la) * 64];
            bf16x8 v0 = ld_bf16x8(vp + ((lg ^ r7) * 8));
            bf16x8 v1 = ld_bf16x8(vp + (((4 + lg) ^ r7) * 8));
            o[dt] = __builtin_amdgcn_mfma_f32_16x16x32_bf16(pa0, v0, o[dt], 0, 0, 0);
            o[dt] = __builtin_amdgcn_mfma_f32_16x16x32_bf16(pa1, v1, o[dt], 0, 0, 0);
        }
        __builtin_amdgcn_s_setprio(0);
    }

    // epilogue: single l-reduce across the 16 la-lanes, then normalize
    #pragma unroll
    for (int off = 1; off < 16; off <<= 1)
        #pragma unroll
        for (int i = 0; i < 4; ++i)
            lpart[i] += __shfl_xor(lpart[i], off, 64);

    #pragma unroll
    for (int dt = 0; dt < 4; ++dt)
        #pragma unroll
        for (int i = 0; i < 4; ++i) {
            int row = qtile + w * 16 + lg * 4 + i;
            float val = o[dt][i] / lpart[i];
            ob[(size_t)row * os + dt * 16 + la] = (bf16_t)val;
        }
}

// ---------------------------------------------------------------------------
extern "C" void kernel_launch(void* const* d_in, const int* in_sizes, int n_in,
                              void* d_out, int out_size, void* d_ws, size_t ws_size,
                              hipStream_t stream)
{
    const float* input     = (const float*)d_in[0];
    const float* source    = (const float*)d_in[1];
    const float* ln_self_w = (const float*)d_in[4];
    const float* ln_self_b = (const float*)d_in[5];
    const float* w_qkv     = (const float*)d_in[6];
    const float* b_qkv     = (const float*)d_in[7];
    const float* w_so      = (const float*)d_in[8];
    const float* b_so      = (const float*)d_in[9];
    const float* ln_cross_w= (const float*)d_in[10];
    const float* ln_cross_b= (const float*)d_in[11];
    const float* w_q       = (const float*)d_in[12];
    const float* b_q       = (const float*)d_in[13];
    const float* w_kv      = (const float*)d_in[14];
    const float* b_kv      = (const float*)d_in[15];
    const float* w_co      = (const float*)d_in[16];
    const float* b_co      = (const float*)d_in[17];
    const float* ln_mlp_w  = (const float*)d_in[18];
    const float* ln_mlp_b  = (const float*)d_in[19];
    const float* w_ff1     = (const float*)d_in[20];
    const float* b_ff1     = (const float*)d_in[21];
    const float* w_ff2     = (const float*)d_in[22];
    const float* b_ff2     = (const float*)d_in[23];

    const int M = NB * NL;   // 4096 rows

    char* ws = (char*)d_ws;
    size_t off = 0;
    auto alloc = [&](size_t bytes) { char* p = ws + off; off += (bytes + 255) & ~(size_t)255; return p; };

    bf16_t* wT_qkv = (bf16_t*)alloc((size_t)3072 * 1024 * 2);
    bf16_t* wT_so  = (bf16_t*)alloc((size_t)1024 * 1024 * 2);
    bf16_t* wT_q   = (bf16_t*)alloc((size_t)1024 * 1024 * 2);
    bf16_t* wT_kv  = (bf16_t*)alloc((size_t)2048 * 1024 * 2);
    bf16_t* wT_co  = (bf16_t*)alloc((size_t)1024 * 1024 * 2);
    bf16_t* wT_ff1 = (bf16_t*)alloc((size_t)4096 * 1024 * 2);
    bf16_t* wT_ff2 = (bf16_t*)alloc((size_t)1024 * 4096 * 2);
    bf16_t* srcb   = (bf16_t*)alloc((size_t)M * 1024 * 2);
    bf16_t* hbuf   = (bf16_t*)alloc((size_t)M * 1024 * 2);
    bf16_t* qkvb   = (bf16_t*)alloc((size_t)M * 3072 * 2);
    bf16_t* attnb  = (bf16_t*)alloc((size_t)M * 1024 * 2);
    bf16_t* qcb    = (bf16_t*)alloc((size_t)M * 1024 * 2);
    bf16_t* kvcb   = (bf16_t*)alloc((size_t)M * 2048 * 2);
    float*  xbuf   = (float*) alloc((size_t)M * 1024 * 4);
    bf16_t* ff1b   = (bf16_t*)alloc((size_t)M * 4096 * 2);
    (void)ws_size; (void)n_in; (void)in_sizes; (void)out_size;

    // weights -> bf16 transposed
    wconv_kernel<<<dim3(3072/32, 1024/32), 256, 0, stream>>>(w_qkv, wT_qkv, 1024, 3072);
    wconv_kernel<<<dim3(1024/32, 1024/32), 256, 0, stream>>>(w_so,  wT_so,  1024, 1024);
    wconv_kernel<<<dim3(1024/32, 1024/32), 256, 0, stream>>>(w_q,   wT_q,   1024, 1024);
    wconv_kernel<<<dim3(2048/32, 1024/32), 256, 0, stream>>>(w_kv,  wT_kv,  1024, 2048);
    wconv_kernel<<<dim3(1024/32, 1024/32), 256, 0, stream>>>(w_co,  wT_co,  1024, 1024);
    wconv_kernel<<<dim3(4096/32, 1024/32), 256, 0, stream>>>(w_ff1, wT_ff1, 1024, 4096);
    wconv_kernel<<<dim3(1024/32, 4096/32), 256, 0, stream>>>(w_ff2, wT_ff2, 4096, 1024);
    // source -> bf16
    f2b_kernel<<<(M * 1024) / (256 * 4), 256, 0, stream>>>(source, srcb);

    // ---- self-attention block ----
    ln_kernel<<<M, 256, 0, stream>>>(input, ln_self_w, ln_self_b, hbuf);
    gemm_kernel<0,128,128><<<dim3(3072/128, M/128), 512, 0, stream>>>(hbuf, wT_qkv, b_qkv, nullptr, qkvb, M, 3072, 1024);
    attn_kernel<true><<<dim3(NL/128, NB*NH), 512, 0, stream>>>(qkvb, 3072, qkvb + 1024, 3072, qkvb + 2048, 3072,
                                                               attnb, 1024, NL, NL);
    gemm_kernel<2,128,64><<<dim3(1024/64, M/128), 512, 0, stream>>>(attnb, wT_so, b_so, input, xbuf, M, 1024, 1024);

    // ---- cross-attention block ----
    ln_kernel<<<M, 256, 0, stream>>>(xbuf, ln_cross_w, ln_cross_b, hbuf);
    gemm_kernel<0,128,64><<<dim3(1024/64, M/128), 512, 0, stream>>>(hbuf, wT_q, b_q, nullptr, qcb, M, 1024, 1024);
    gemm_kernel<0,128,128><<<dim3(2048/128, M/128), 512, 0, stream>>>(srcb, wT_kv, b_kv, nullptr, kvcb, M, 2048, 1024);
    attn_kernel<false><<<dim3(NL/128, NB*NH), 512, 0, stream>>>(qcb, 1024, kvcb, 2048, kvcb + 1024, 2048,
                                                                attnb, 1024, NL, NS);
    gemm_kernel<2,128,64><<<dim3(1024/64, M/128), 512, 0, stream>>>(attnb, wT_co, b_co, xbuf, xbuf, M, 1024, 1024);

    // ---- MLP block ----
    ln_kernel<<<M, 256, 0, stream>>>(xbuf, ln_mlp_w, ln_mlp_b, hbuf);
    gemm_kernel<1,128,128><<<dim3(4096/128, M/128), 512, 0, stream>>>(hbuf, wT_ff1, b_ff1, nullptr, ff1b, M, 4096, 1024);
    gemm_kernel<2,128,64><<<dim3(1024/64, M/128), 512, 0, stream>>>(ff1b, wT_ff2, b_ff2, xbuf, d_out, M, 1024, 4096);
}